// Round 11
// baseline (422.964 us; speedup 1.0000x reference)
//
#include <hip/hip_runtime.h>
#include <hip/hip_bf16.h>

typedef __attribute__((ext_vector_type(8))) short bf16x8;
typedef __attribute__((ext_vector_type(4))) short bf16x4;
typedef __attribute__((ext_vector_type(4))) float f32x4;

#define B_ 4
#define N_ 16000
#define C_ 128
#define K_ 16
#define D_ 4
#define H_ 512
#define R_ (B_*N_)      // 64000 rows
#define EPSV 1e-5f

__device__ __forceinline__ ushort f2bf(float f) {
    uint32_t b = __builtin_bit_cast(uint32_t, f);
    b += 0x7fffu + ((b >> 16) & 1u);   // RNE
    return (ushort)(b >> 16);
}
__device__ __forceinline__ float bf2f(ushort u) {
    return __builtin_bit_cast(float, (uint32_t)u << 16);
}
// packed RNE pair (scalar impl — proven semantics)
__device__ __forceinline__ uint pk2bf(float lo, float hi) {
    return (uint)f2bf(lo) | ((uint)f2bf(hi) << 16);
}
// gelu_tanh(v) = v * sigmoid(2u), u = 0.79788456*(v + 0.044715 v^3)
__device__ __forceinline__ float gelu_fast(float v) {
    float v2 = v * v;
    float u = v * fmaf(0.0356774081f, v2, 0.7978845608f);
    float e = __expf(-2.0f * u);
    return v * __builtin_amdgcn_rcpf(1.0f + e);
}
// async global->LDS, 16B per lane; lds base must be wave-uniform
__device__ __forceinline__ void gll16(const void* g, void* l) {
    __builtin_amdgcn_global_load_lds(
        (__attribute__((address_space(1))) void*)g,
        (__attribute__((address_space(3))) void*)l, 16, 0, 0);
}

// ---------------- prep: transpose weights bf16, fold BN ----------------
// sigma-permutation (within each 32-k block): slot s=8*lam+j holds
// k = 4*lam + (j&3) + 16*(j>>2). Applied to W2's h-dim ONLY (GEMM2's A comes
// register-locally from GEMM1's accumulator fragments). Wv is a natural
// transpose: GEMM3's A is re-read from LDS in natural k-order.
__global__ void prep_kernel(
    const float* __restrict__ mlp_W1, const float* __restrict__ mlp_b1,
    const float* __restrict__ mlp_W2, const float* __restrict__ mlp_g,
    const float* __restrict__ mlp_be, const float* __restrict__ mlp_m,
    const float* __restrict__ mlp_v,
    const float* __restrict__ vfr_W, const float* __restrict__ vfr_g,
    const float* __restrict__ vfr_be, const float* __restrict__ vfr_m,
    const float* __restrict__ vfr_v,
    const float* __restrict__ ffn_W1, const float* __restrict__ ffn_b1,
    const float* __restrict__ ffn_W2, const float* __restrict__ ffn_g,
    const float* __restrict__ ffn_be, const float* __restrict__ ffn_m,
    const float* __restrict__ ffn_v,
    ushort* __restrict__ w1t, ushort* __restrict__ w2p, ushort* __restrict__ wvt,
    float* __restrict__ b1a, float* __restrict__ fs, float* __restrict__ fb,
    float* __restrict__ vs, float* __restrict__ vb)
{
    int i = blockIdx.x * 256 + threadIdx.x;
    const int NW = 5 * H_ * C_;   // 327680
    if (i < NW) {                 // w1t[f][h][c] = W1_f[c][h]
        int f = i / (H_*C_), e = i % (H_*C_);
        int h = e / C_, c = e % C_;
        const float* src = (f == 0) ? mlp_W1 : ffn_W1 + (size_t)(f-1)*C_*H_;
        w1t[i] = f2bf(src[(size_t)c*H_ + h]);
        return;
    }
    i -= NW;
    if (i < NW) {                 // w2p[f][c][p] = W2_f[sigma(p)][c]
        int f = i / (H_*C_), e = i % (H_*C_);
        int c = e / H_, p = e % H_;
        int s = p & 31, lam = s >> 3, j = s & 7;
        int h = (p & ~31) + lam*4 + (j & 3) + ((j >> 2) << 4);
        const float* src = (f == 0) ? mlp_W2 : ffn_W2 + (size_t)(f-1)*H_*C_;
        w2p[i] = f2bf(src[(size_t)h*C_ + c]);
        return;
    }
    i -= NW;
    if (i < D_*C_*C_) {           // wvt[d][cout][k] = W[d][k][cout]  (natural)
        int d = i / (C_*C_), e = i % (C_*C_);
        int co = e / C_, k = e % C_;
        wvt[i] = f2bf(vfr_W[(size_t)d*C_*C_ + (size_t)k*C_ + co]);
        return;
    }
    i -= D_*C_*C_;
    if (i < 5*H_) {               // biases
        int f = i / H_, h = i % H_;
        b1a[i] = (f == 0) ? mlp_b1[h] : ffn_b1[(f-1)*H_ + h];
        return;
    }
    i -= 5*H_;
    if (i < 5*C_) {               // ffn BN: y*s + b
        int f = i / C_, c = i % C_;
        float g  = (f==0) ? mlp_g[c]  : ffn_g[(f-1)*C_ + c];
        float be = (f==0) ? mlp_be[c] : ffn_be[(f-1)*C_ + c];
        float m  = (f==0) ? mlp_m[c]  : ffn_m[(f-1)*C_ + c];
        float v  = (f==0) ? mlp_v[c]  : ffn_v[(f-1)*C_ + c];
        float s = g * rsqrtf(v + EPSV);
        fs[i] = s; fb[i] = be - m * s;
        return;
    }
    i -= 5*C_;
    if (i < D_*C_) {              // vfr BN
        float s = vfr_g[i] * rsqrtf(vfr_v[i] + EPSV);
        vs[i] = s; vb[i] = vfr_be[i] - vfr_m[i] * s;
    }
}

// ---- fused FFN (+ next-depth t-GEMM), COALESCED activation I/O:
//   x_out = x_in [+ pe] + BN(gelu(x_in@W1+b1)@W2);  if NEXT_T: t = bf16(x_out @ Wv)
// All global x/pe/xout/t accesses are wave-coalesced (lane -> contiguous 16B
// within a row; 64 lanes = 2-4 full rows per instruction). MFMA fragment
// layouts are produced/consumed via swizzled LDS redistributions, with the
// 32KB LDS region time-multiplexed: xsb -> W-dbuf (r10's counted-vmcnt loop,
// verbatim) -> Y-fp32 -> {xob | Wv halves} -> t16.
template<bool ADD_PE, bool NEXT_T>
__global__ __launch_bounds__(256, 3) void ffn_kernel(
    const float* __restrict__ xin, float* __restrict__ xout,
    const float* __restrict__ pe,
    const ushort* __restrict__ W1t,   // [H][C] bf16
    const ushort* __restrict__ W2p,   // [C][H] bf16, sigma-permuted in h
    const float* __restrict__ b1,
    const float* __restrict__ bns, const float* __restrict__ bnb,
    const ushort* __restrict__ Wvt,   // [C][C] bf16, natural [cout][k]
    ushort* __restrict__ tout)
{
    __shared__ __attribute__((aligned(16))) char lds[32768];

    const int tid  = threadIdx.x;
    const int m0   = blockIdx.x * 64;
    const int wv   = tid >> 6;
    const int lane = tid & 63;
    const int lr   = lane & 15;
    const int lh   = lane >> 4;       // 0..3
    const int crow = tid >> 5;        // coalesced mapping: 8 rows per step
    const int ccol = (tid & 31) * 4;  // fp32 column

    // ---- stage chunk hc's W tiles (32 h) into buffer buf ----
    auto stageW = [&](int hc, int buf) {
        char* base = lds + buf * 16384;
        const int h0 = hc * 32;
        #pragma unroll
        for (int i = 0; i < 2; ++i) {      // W1s: [32 h][256B] swizzled
            int row = i*16 + wv*4 + (lane >> 4);
            const char* src = (const char*)(W1t + (size_t)(h0 + row) * C_)
                            + (((lane & 15) * 16) ^ ((row & 7) << 4));
            gll16(src, base + i*4096 + wv*1024);
        }
        #pragma unroll
        for (int i = 0; i < 2; ++i) {      // W2s: [128 c][64B] swizzled (4-way ok)
            int c = i*64 + wv*16 + (lane >> 2);
            const char* src = (const char*)(W2p + (size_t)c * H_ + h0)
                            + (((lane & 3) * 16) ^ ((c & 3) << 4));
            gll16(src, base + 8192 + i*4096 + wv*1024);
        }
    };
    // Wv half h (couts h*64..h*64+63): [64 rows][256B] swizzled at lds+16K
    auto stageWvHalf = [&](int h) {
        #pragma unroll
        for (int i = 0; i < 4; ++i) {
            int r = i*16 + wv*4 + (lane >> 4);
            const char* src = (const char*)(Wvt + (size_t)(h*64 + r) * C_)
                            + (((lane & 15) * 16) ^ ((r & 7) << 4));
            gll16(src, lds + 16384 + i*4096 + wv*1024);
        }
    };

    // ---- 1. coalesced x(+pe) load; base in regs; pack x -> xsb LDS ----
    float4 base[8];
    #pragma unroll
    for (int s = 0; s < 8; ++s) {
        int row = s*8 + crow;
        size_t go = (size_t)(m0 + row) * C_ + ccol;
        float4 xv = *(const float4*)(xin + go);
        float4 bp = xv;
        if (ADD_PE) {
            float4 pv = *(const float4*)(pe + go);
            bp.x += pv.x; bp.y += pv.y; bp.z += pv.z; bp.w += pv.w;
        }
        base[s] = bp;
        uint2 u = { pk2bf(xv.x, xv.y), pk2bf(xv.z, xv.w) };   // bf16(x), no pe
        *(uint2*)(lds + row*256 + ((ccol*2) ^ ((row&7)<<4))) = u;
    }
    __syncthreads();

    // ---- 2. A-fragments from xsb ----
    bf16x8 xa[4];
    {
        const int arow = wv*16 + lr;
        #pragma unroll
        for (int kk = 0; kk < 4; ++kk)
            xa[kk] = *(bf16x8*)(lds + arow*256 + ((kk*64 + lh*16) ^ ((arow&7)<<4)));
    }
    __syncthreads();   // xsb free -> region becomes W double-buffer

    stageW(0, 0);      // prologue prefetch

    f32x4 acc2[8];
    #pragma unroll
    for (int i = 0; i < 8; ++i) acc2[i] = (f32x4){0.f,0.f,0.f,0.f};

    // ---- 3. r10 counted-vmcnt chunk loop (proven) ----
    #pragma unroll 1
    for (int hc = 0; hc < 16; ++hc) {
        const int h0  = hc * 32;
        const int buf = hc & 1;

        float4 biasv[2];
        #pragma unroll
        for (int nf = 0; nf < 2; ++nf)
            biasv[nf] = *(const float4*)(b1 + h0 + nf*16 + lh*4);
        __builtin_amdgcn_sched_barrier(0);

        if (hc < 15) {
            stageW(hc + 1, buf ^ 1);
            asm volatile("s_waitcnt vmcnt(6)" ::: "memory");   // chunk hc landed
        } else {
            asm volatile("s_waitcnt vmcnt(2)" ::: "memory");
        }
        __builtin_amdgcn_s_barrier();
        __builtin_amdgcn_sched_barrier(0);

        char* W1s = lds + buf * 16384;
        char* W2s = W1s + 8192;

        f32x4 acc1[2];
        #pragma unroll
        for (int i = 0; i < 2; ++i) acc1[i] = (f32x4){0.f,0.f,0.f,0.f};
        #pragma unroll
        for (int kk = 0; kk < 4; ++kk) {
            int kb = kk*64 + lh*16;
            #pragma unroll
            for (int nf = 0; nf < 2; ++nf) {
                int rb = nf*16 + lr;
                bf16x8 w1 = *(bf16x8*)(W1s + rb*256 + (kb ^ ((rb&7)<<4)));
                acc1[nf] = __builtin_amdgcn_mfma_f32_16x16x32_bf16(
                    w1, xa[kk], acc1[nf], 0, 0, 0);
            }
        }
        bf16x4 pa[2];
        #pragma unroll
        for (int nf = 0; nf < 2; ++nf) {
            uint q0 = pk2bf(gelu_fast(acc1[nf][0] + biasv[nf].x),
                            gelu_fast(acc1[nf][1] + biasv[nf].y));
            uint q1 = pk2bf(gelu_fast(acc1[nf][2] + biasv[nf].z),
                            gelu_fast(acc1[nf][3] + biasv[nf].w));
            uint2 u = {q0, q1};
            pa[nf] = __builtin_bit_cast(bf16x4, u);
        }
        {
            bf16x8 af = __builtin_shufflevector(pa[0], pa[1], 0,1,2,3,4,5,6,7);
            #pragma unroll
            for (int nf = 0; nf < 8; ++nf) {
                int rb = nf*16 + lr;
                bf16x8 w2 = *(bf16x8*)(W2s + rb*64 + ((lh*16) ^ ((rb&3)<<4)));
                acc2[nf] = __builtin_amdgcn_mfma_f32_16x16x32_bf16(
                    w2, af, acc2[nf], 0, 0, 0);
            }
        }

        __builtin_amdgcn_sched_barrier(0);
        asm volatile("s_waitcnt lgkmcnt(0)" ::: "memory");
        __builtin_amdgcn_s_barrier();
    }

    // ---- 4. BN(Y) -> LDS fp32 [64 rows][512B] (full 32KB, swizzled) ----
    {
        const int yrow = wv*16 + lr;
        #pragma unroll
        for (int nf = 0; nf < 8; ++nf) {
            int c0 = nf*16 + lh*4;
            float4 sv = *(const float4*)(bns + c0);
            float4 bv = *(const float4*)(bnb + c0);
            f32x4 yv;
            yv[0] = acc2[nf][0] * sv.x + bv.x;
            yv[1] = acc2[nf][1] * sv.y + bv.y;
            yv[2] = acc2[nf][2] * sv.z + bv.z;
            yv[3] = acc2[nf][3] * sv.w + bv.w;
            *(f32x4*)(lds + yrow*512 + ((nf*64 + lh*16) ^ ((yrow&7)<<4))) = yv;
        }
    }
    __syncthreads();

    // ---- 5. coalesced: xo = base + y; store x_out; xo kept in base[] ----
    #pragma unroll
    for (int s = 0; s < 8; ++s) {
        int row = s*8 + crow;
        f32x4 yv = *(f32x4*)(lds + row*512 + ((ccol*4) ^ ((row&7)<<4)));
        float4 xo;
        xo.x = base[s].x + yv[0];
        xo.y = base[s].y + yv[1];
        xo.z = base[s].z + yv[2];
        xo.w = base[s].w + yv[3];
        *(float4*)(xout + (size_t)(m0 + row) * C_ + ccol) = xo;
        base[s] = xo;
    }
    if (!NEXT_T) return;

    __syncthreads();   // all Y reads done -> region reusable

    // ---- 6. xob (bf16 x_out) -> LDS [0,16K); stage Wv half 1 -> [16K,32K) ----
    #pragma unroll
    for (int s = 0; s < 8; ++s) {
        int row = s*8 + crow;
        uint2 u = { pk2bf(base[s].x, base[s].y), pk2bf(base[s].z, base[s].w) };
        *(uint2*)(lds + row*256 + ((ccol*2) ^ ((row&7)<<4))) = u;
    }
    stageWvHalf(0);
    __syncthreads();   // xob visible + Wv half1 landed (full drain, once)

    // ---- 7. GEMM3: A-frags from xob (natural consecutive k), two Wv halves ----
    bf16x8 af3[4];
    {
        const int arow = wv*16 + lr;
        #pragma unroll
        for (int g = 0; g < 4; ++g)
            af3[g] = *(bf16x8*)(lds + arow*256 + ((g*64 + lh*16) ^ ((arow&7)<<4)));
    }
    f32x4 acc3[8];
    #pragma unroll
    for (int i = 0; i < 8; ++i) acc3[i] = (f32x4){0.f,0.f,0.f,0.f};
    #pragma unroll
    for (int g = 0; g < 4; ++g) {
        int kb = g*64 + lh*16;
        #pragma unroll
        for (int nf = 0; nf < 4; ++nf) {
            int rb = nf*16 + lr;
            bf16x8 wvf = *(bf16x8*)(lds + 16384 + rb*256 + (kb ^ ((rb&7)<<4)));
            acc3[nf] = __builtin_amdgcn_mfma_f32_16x16x32_bf16(
                af3[g], wvf, acc3[nf], 0, 0, 0);
        }
    }
    __syncthreads();   // half1 reads done
    stageWvHalf(1);
    __syncthreads();   // half2 landed
    #pragma unroll
    for (int g = 0; g < 4; ++g) {
        int kb = g*64 + lh*16;
        #pragma unroll
        for (int nf = 4; nf < 8; ++nf) {
            int rb = (nf-4)*16 + lr;
            bf16x8 wvf = *(bf16x8*)(lds + 16384 + rb*256 + (kb ^ ((rb&7)<<4)));
            acc3[nf] = __builtin_amdgcn_mfma_f32_16x16x32_bf16(
                af3[g], wvf, acc3[nf], 0, 0, 0);
        }
    }

    // ---- 8. t16 redistribute -> coalesced t stores ----
    #pragma unroll
    for (int nf = 0; nf < 8; ++nf) {
        int col = nf*16 + lr;
        #pragma unroll
        for (int j = 0; j < 4; ++j) {
            int trow = wv*16 + lh*4 + j;
            *(ushort*)(lds + trow*256 + ((col*2) ^ ((trow&7)<<4))) = f2bf(acc3[nf][j]);
        }
    }
    __syncthreads();
    #pragma unroll
    for (int s = 0; s < 4; ++s) {
        int trow = s*16 + (tid >> 4);
        int tb   = (tid & 15) * 16;
        uint4 v = *(uint4*)(lds + trow*256 + (tb ^ ((trow&7)<<4)));
        *(uint4*)((char*)(tout + (size_t)(m0 + trow) * C_) + tb) = v;
    }
}

// ---------------- vfr gather: x += BN(max_k t[knn] - t) ----------------
__global__ __launch_bounds__(256) void vfr_gather_kernel(
    float* __restrict__ x, const ushort* __restrict__ t,
    const int* __restrict__ knn,
    const float* __restrict__ s, const float* __restrict__ bb)
{
    const int wv   = threadIdx.x >> 6;
    const int lane = threadIdx.x & 63;
    const int p = blockIdx.x * 4 + wv;          // point id 0..63999
    const int b = p / N_;
    const int base = b * N_;
    const int* kp = knn + (size_t)p * K_;
    const uint* trow = (const uint*)t;          // 64 dwords per row

    uint cen = trow[(size_t)p * 64 + lane];
    float c0 = bf2f((ushort)(cen & 0xffffu));
    float c1 = bf2f((ushort)(cen >> 16));
    float m0v = -INFINITY, m1v = -INFINITY;
    #pragma unroll
    for (int k = 0; k < K_; ++k) {
        int idx = kp[k];
        uint g = trow[(size_t)(base + idx) * 64 + lane];
        m0v = fmaxf(m0v, bf2f((ushort)(g & 0xffffu)));
        m1v = fmaxf(m1v, bf2f((ushort)(g >> 16)));
    }
    m0v -= c0; m1v -= c1;

    int c = lane * 2;
    float2 sv = *(const float2*)(s + c);
    float2 bv = *(const float2*)(bb + c);
    size_t o = (size_t)p * C_ + c;
    float2 xv = *(const float2*)(x + o);
    xv.x += m0v * sv.x + bv.x;
    xv.y += m1v * sv.y + bv.y;
    *(float2*)(x + o) = xv;
}

extern "C" void kernel_launch(void* const* d_in, const int* in_sizes, int n_in,
                              void* d_out, int out_size, void* d_ws, size_t ws_size,
                              hipStream_t stream) {
    const float* x      = (const float*)d_in[0];
    const float* pe     = (const float*)d_in[1];
    const int*   knn    = (const int*)d_in[2];
    const float* mlp_W1 = (const float*)d_in[3];
    const float* mlp_b1 = (const float*)d_in[4];
    const float* mlp_W2 = (const float*)d_in[5];
    const float* mlp_g  = (const float*)d_in[6];
    const float* mlp_be = (const float*)d_in[7];
    const float* mlp_m  = (const float*)d_in[8];
    const float* mlp_v  = (const float*)d_in[9];
    const float* vfr_W  = (const float*)d_in[10];
    const float* vfr_g  = (const float*)d_in[11];
    const float* vfr_be = (const float*)d_in[12];
    const float* vfr_m  = (const float*)d_in[13];
    const float* vfr_v  = (const float*)d_in[14];
    const float* ffn_W1 = (const float*)d_in[15];
    const float* ffn_b1 = (const float*)d_in[16];
    const float* ffn_W2 = (const float*)d_in[17];
    const float* ffn_g  = (const float*)d_in[18];
    const float* ffn_be = (const float*)d_in[19];
    const float* ffn_m  = (const float*)d_in[20];
    const float* ffn_v  = (const float*)d_in[21];
    float* out = (float*)d_out;

    char* ws = (char*)d_ws;
    ushort* tbuf = (ushort*)ws;  ws += (size_t)R_ * C_ * 2;       // 16.4 MB
    ushort* w1t  = (ushort*)ws;  ws += (size_t)5 * H_ * C_ * 2;
    ushort* w2p  = (ushort*)ws;  ws += (size_t)5 * C_ * H_ * 2;
    ushort* wvt  = (ushort*)ws;  ws += (size_t)D_ * C_ * C_ * 2;
    float*  b1a  = (float*)ws;   ws += (size_t)5 * H_ * 4;
    float*  fs   = (float*)ws;   ws += (size_t)5 * C_ * 4;
    float*  fb   = (float*)ws;   ws += (size_t)5 * C_ * 4;
    float*  vs   = (float*)ws;   ws += (size_t)D_ * C_ * 4;
    float*  vb   = (float*)ws;   ws += (size_t)D_ * C_ * 4;

    const int prep_items = 2*(5*H_*C_) + D_*C_*C_ + 5*H_ + 5*C_ + D_*C_;
    prep_kernel<<<(prep_items + 255) / 256, 256, 0, stream>>>(
        mlp_W1, mlp_b1, mlp_W2, mlp_g, mlp_be, mlp_m, mlp_v,
        vfr_W, vfr_g, vfr_be, vfr_m, vfr_v,
        ffn_W1, ffn_b1, ffn_W2, ffn_g, ffn_be, ffn_m, ffn_v,
        w1t, w2p, wvt, b1a, fs, fb, vs, vb);

    // x1 = x0 + FFN_mlp(x0) + pe ; t0 = x1 @ Wv0 fused
    ffn_kernel<true, true><<<R_/64, 256, 0, stream>>>(
        x, out, pe, w1t, w2p, b1a, fs, fb, wvt, tbuf);

    for (int d = 0; d < D_; ++d) {
        vfr_gather_kernel<<<R_/4, 256, 0, stream>>>(
            out, tbuf, knn, vs + d * C_, vb + d * C_);
        if (d < D_ - 1) {
            ffn_kernel<true, true><<<R_/64, 256, 0, stream>>>(
                out, out, pe,
                w1t + (size_t)(d+1) * H_ * C_, w2p + (size_t)(d+1) * C_ * H_,
                b1a + (d+1) * H_, fs + (d+1) * C_, fb + (d+1) * C_,
                wvt + (size_t)(d+1) * C_ * C_, tbuf);
        } else {
            ffn_kernel<false, false><<<R_/64, 256, 0, stream>>>(
                out, out, pe,
                w1t + (size_t)(d+1) * H_ * C_, w2p + (size_t)(d+1) * C_ * H_,
                b1a + (d+1) * H_, fs + (d+1) * C_, fb + (d+1) * C_,
                wvt, tbuf);
        }
    }
}